// Round 13
// baseline (2336.286 us; speedup 1.0000x reference)
//
#include <hip/hip_runtime.h>
#include <cmath>
#include <cstdint>

#define VOCAB 32000
#define HID   1024
#define BATCH 16
#define SEQ   256
#define NL0   64
#define NL1   128
#define MASTER 192                 // block 192: sync master (then scavenges)
#define NBLK  256                  // 64 L0 + 128 L1 + 1 master + 63 helpers
#define BH    (BATCH * HID)
#define NTILE_M 16
#define NTILE_N 125
#define NTILES  (NTILE_M * NTILE_N)   // 2000 proj tiles (256x256)

typedef __attribute__((ext_vector_type(8))) short short8;
typedef __attribute__((ext_vector_type(4))) float f32x4;

__device__ __forceinline__ ushort f2bf(float f) {  // RNE fp32 -> bf16 bits
  uint u = __builtin_bit_cast(uint, f);
  return (ushort)((u + 0x7FFFu + ((u >> 16) & 1u)) >> 16);
}
__device__ __forceinline__ float bf2f(ushort h) {
  return __builtin_bit_cast(float, (uint)h << 16);
}

// ---- MALL-coherent vector load/store (sc0 sc1), early-clobber outputs ----
#define LOAD8(d, base)                                                        \
  asm volatile(                                                               \
    "global_load_dwordx4 %0, %8, off sc0 sc1\n\t"                             \
    "global_load_dwordx4 %1, %8, off offset:512 sc0 sc1\n\t"                  \
    "global_load_dwordx4 %2, %8, off offset:1024 sc0 sc1\n\t"                 \
    "global_load_dwordx4 %3, %8, off offset:1536 sc0 sc1\n\t"                 \
    "global_load_dwordx4 %4, %8, off offset:2048 sc0 sc1\n\t"                 \
    "global_load_dwordx4 %5, %8, off offset:2560 sc0 sc1\n\t"                 \
    "global_load_dwordx4 %6, %8, off offset:3072 sc0 sc1\n\t"                 \
    "global_load_dwordx4 %7, %8, off offset:3584 sc0 sc1"                     \
    : "=&v"(d[0]), "=&v"(d[1]), "=&v"(d[2]), "=&v"(d[3]),                     \
      "=&v"(d[4]), "=&v"(d[5]), "=&v"(d[6]), "=&v"(d[7])                      \
    : "v"(base) : "memory")

#define WAIT8(d)                                                              \
  asm volatile("s_waitcnt vmcnt(0)"                                           \
    : "+v"(d[0]), "+v"(d[1]), "+v"(d[2]), "+v"(d[3]),                         \
      "+v"(d[4]), "+v"(d[5]), "+v"(d[6]), "+v"(d[7]) :: "memory")

__device__ __forceinline__ void st_coherent(float* p, float v) {
  asm volatile("global_store_dword %0, %1, off sc0 sc1" :: "v"(p), "v"(v) : "memory");
}
__device__ __forceinline__ void st_coherent_u16(ushort* p, ushort v) {
  asm volatile("global_store_short %0, %1, off sc0 sc1" :: "v"(p), "v"((uint)v) : "memory");
}
__device__ __forceinline__ void st_nt(float* p, float v) {   // evict-first
  asm volatile("global_store_dword %0, %1, off nt" :: "v"(p), "v"(v) : "memory");
}
__device__ __forceinline__ int ld_rlx(const int* p) {
  return __hip_atomic_load(p, __ATOMIC_RELAXED, __HIP_MEMORY_SCOPE_AGENT);
}
__device__ __forceinline__ void st_rlx(int* p, int v) {
  __hip_atomic_store(p, v, __ATOMIC_RELAXED, __HIP_MEMORY_SCOPE_AGENT);
}

// ---------------------------------------------------------------------------
// pre0[t][b][n] = embed[x[b][t]] . Wi0[n] + bi0[n] + bh0[n]   (unchanged)
// ---------------------------------------------------------------------------
__global__ __launch_bounds__(256) void pre0_gemm(
    const int* __restrict__ x, const float* __restrict__ embed,
    const float* __restrict__ Wi0, const float* __restrict__ bi0,
    const float* __restrict__ bh0, float* __restrict__ pre)
{
  __shared__ float As[32][132];
  __shared__ float Bs[32][132];
  const int tid  = threadIdx.x;
  const int n0   = blockIdx.x * 128;
  const int m0   = blockIdx.y * 128;
  const int lrow = tid >> 3, lkq = tid & 7;
  const int ty   = tid >> 4, tx  = tid & 15;

  const float* arow[4];
#pragma unroll
  for (int q = 0; q < 4; ++q) {
    int m = m0 + lrow + 32 * q;
    int t = m >> 4, b = m & 15;
    arow[q] = embed + (size_t)x[b * SEQ + t] * HID;
  }
  const float* brow = Wi0 + (size_t)(n0 + lrow) * HID;

  float acc[8][8];
#pragma unroll
  for (int i = 0; i < 8; ++i)
#pragma unroll
    for (int j = 0; j < 8; ++j) acc[i][j] = 0.f;

  for (int kt = 0; kt < HID; kt += 32) {
    float4 av[4], bv[4];
#pragma unroll
    for (int q = 0; q < 4; ++q) {
      av[q] = *(const float4*)(arow[q] + kt + lkq * 4);
      bv[q] = *(const float4*)(brow + (size_t)(32 * q) * HID + kt + lkq * 4);
    }
    __syncthreads();
#pragma unroll
    for (int q = 0; q < 4; ++q) {
      int r = lrow + 32 * q;
      As[lkq*4+0][r] = av[q].x; As[lkq*4+1][r] = av[q].y;
      As[lkq*4+2][r] = av[q].z; As[lkq*4+3][r] = av[q].w;
      Bs[lkq*4+0][r] = bv[q].x; Bs[lkq*4+1][r] = bv[q].y;
      Bs[lkq*4+2][r] = bv[q].z; Bs[lkq*4+3][r] = bv[q].w;
    }
    __syncthreads();
#pragma unroll
    for (int kk = 0; kk < 32; ++kk) {
      float4 a0 = *(const float4*)&As[kk][ty * 8];
      float4 a1 = *(const float4*)&As[kk][ty * 8 + 4];
      float4 b0 = *(const float4*)&Bs[kk][tx * 8];
      float4 b1 = *(const float4*)&Bs[kk][tx * 8 + 4];
      float a[8] = {a0.x,a0.y,a0.z,a0.w,a1.x,a1.y,a1.z,a1.w};
      float b[8] = {b0.x,b0.y,b0.z,b0.w,b1.x,b1.y,b1.z,b1.w};
#pragma unroll
      for (int i = 0; i < 8; ++i)
#pragma unroll
        for (int j = 0; j < 8; ++j) acc[i][j] = fmaf(a[i], b[j], acc[i][j]);
    }
  }

#pragma unroll
  for (int i = 0; i < 8; ++i) {
    int m = m0 + ty * 8 + i;
    float* o = pre + (size_t)m * HID + n0 + tx * 8;
#pragma unroll
    for (int j = 0; j < 8; ++j) {
      int n = n0 + tx * 8 + j;
      o[j] = acc[i][j] + bi0[n] + bh0[n];
    }
  }
}

// Wo (f32) -> WoH (bf16 RNE), one-time. 32000*1024 = 32,768,000 elems.
__global__ __launch_bounds__(256) void wo_conv(
    const float* __restrict__ Wo, ushort* __restrict__ WoH)
{
  const size_t total = (size_t)VOCAB * HID;
  for (size_t i = ((size_t)blockIdx.x * 256 + threadIdx.x) * 8; i < total;
       i += (size_t)gridDim.x * 256 * 8) {
    float4 v0 = *(const float4*)(Wo + i);
    float4 v1 = *(const float4*)(Wo + i + 4);
    short8 w;
    w[0] = (short)f2bf(v0.x); w[1] = (short)f2bf(v0.y);
    w[2] = (short)f2bf(v0.z); w[3] = (short)f2bf(v0.w);
    w[4] = (short)f2bf(v1.x); w[5] = (short)f2bf(v1.y);
    w[6] = (short)f2bf(v1.z); w[7] = (short)f2bf(v1.w);
    *(short8*)(WoH + i) = w;
  }
}

// ---------------------------------------------------------------------------
// Fused cooperative kernel: decoupled 2-cohort scan + proj scavenging.
//  bar lines (128B): 0..3 L0 arrivals, 4..11 L1 arrivals, 12..19 go0 replicas,
//  20..27 go1 replicas, 28 proj ticket counter.
//  proj C-writes are NON-TEMPORAL (evict-first) so the 512MB logit stream
//  doesn't evict the 64MB WoH panel set from MALL; ticket order is
//  SERPENTINE in nt across mt generations for B-panel temporal locality.
// ---------------------------------------------------------------------------
__global__ __launch_bounds__(512) void rnn_scan(
    const float* __restrict__ Wi, const float* __restrict__ Wh,
    const float* __restrict__ bi, const float* __restrict__ bh,
    const float* __restrict__ pre0, float* __restrict__ h0ring,
    float* __restrict__ h1g, ushort* __restrict__ topsHi,
    ushort* __restrict__ topsLo, const float* __restrict__ Wo,
    const ushort* __restrict__ WoH, const float* __restrict__ bo,
    float* __restrict__ out, int* __restrict__ bar)
{
  __shared__ __align__(16) char pool[139328];   // scan 136.1KB ; proj 96KB
  __shared__ int tkt_s;
  const int tid = threadIdx.x;
  const int blk = blockIdx.x;
  const int rep = (blk & 7) * 32;
  int* go0r = bar + 12 * 32 + rep;
  int* go1r = bar + 20 * 32 + rep;
  int* ticket = bar + 28 * 32;

  // ---------------- proj scavenger (all blocks eventually run this) --------
  auto proj_tiles = [&]() {
    ushort* Ahi = (ushort*)pool;               // 32 KiB each
    ushort* Alo = Ahi + 16384;
    ushort* Bs  = Alo + 16384;
    const int lane = tid & 63, wv = tid >> 6;
    const int wm = wv & 3, wn = wv >> 2;
    const int sr8 = tid >> 3;                  // row base 0..63
    const int sk8 = (tid & 7) * 8;             // k offset 0..56
    for (;;) {
      if (tid == 0)
        tkt_s = __hip_atomic_fetch_add(ticket, 1, __ATOMIC_RELAXED,
                                       __HIP_MEMORY_SCOPE_AGENT);
      __syncthreads();
      const int T = tkt_s;
      if (T >= NTILES) break;
      const int mt = T / NTILE_N;
      const int ntIdx = T % NTILE_N;
      const int nt = (mt & 1) ? (NTILE_N - 1 - ntIdx) : ntIdx;  // serpentine
      if (tid == 0) {
        const int need = 16 * (mt + 1);
        while (ld_rlx(go1r) < need) __builtin_amdgcn_s_sleep(4);
      }
      __syncthreads();                         // gate passed; guards tkt_s
      const int m0 = mt * 256, n0 = nt * 256;

      f32x4 acc[4][8];
#pragma unroll
      for (int i = 0; i < 4; ++i)
#pragma unroll
        for (int j = 0; j < 8; ++j) acc[i][j] = (f32x4)0.f;

      for (int kt = 0; kt < HID; kt += 64) {
        __syncthreads();
#pragma unroll
        for (int p = 0; p < 4; ++p) {          // stage A hi/lo + B, no convert
          int r = sr8 + 64 * p;
          uint off = (uint)(r * 128 + sk8 * 2) ^ (uint)((r & 7) << 4);
          *(short8*)((char*)Ahi + off) =
              *(const short8*)(topsHi + (size_t)(m0 + r) * HID + kt + sk8);
          *(short8*)((char*)Alo + off) =
              *(const short8*)(topsLo + (size_t)(m0 + r) * HID + kt + sk8);
          if (WoH) {
            *(short8*)((char*)Bs + off) =
                *(const short8*)(WoH + (size_t)(n0 + r) * HID + kt + sk8);
          } else {
            float4 v0 = *(const float4*)(Wo + (size_t)(n0 + r) * HID + kt + sk8);
            float4 v1 = *(const float4*)(Wo + (size_t)(n0 + r) * HID + kt + sk8 + 4);
            short8 w;
            w[0] = (short)f2bf(v0.x); w[1] = (short)f2bf(v0.y);
            w[2] = (short)f2bf(v0.z); w[3] = (short)f2bf(v0.w);
            w[4] = (short)f2bf(v1.x); w[5] = (short)f2bf(v1.y);
            w[6] = (short)f2bf(v1.z); w[7] = (short)f2bf(v1.w);
            *(short8*)((char*)Bs + off) = w;
          }
        }
        __syncthreads();

        const int fr = lane & 15, kg = lane >> 4;
#pragma unroll
        for (int kk = 0; kk < 2; ++kk) {
          short8 bf[8], ah[4], al[4];
#pragma unroll
          for (int nf = 0; nf < 8; ++nf) {
            int row = wn * 128 + nf * 16 + fr;
            uint off = (uint)(row * 128 + kk * 64 + kg * 16) ^ (uint)((row & 7) << 4);
            bf[nf] = *(const short8*)((const char*)Bs + off);
          }
#pragma unroll
          for (int mf = 0; mf < 4; ++mf) {
            int row = wm * 64 + mf * 16 + fr;
            uint off = (uint)(row * 128 + kk * 64 + kg * 16) ^ (uint)((row & 7) << 4);
            ah[mf] = *(const short8*)((const char*)Ahi + off);
            al[mf] = *(const short8*)((const char*)Alo + off);
          }
#pragma unroll
          for (int mf = 0; mf < 4; ++mf)
#pragma unroll
            for (int nf = 0; nf < 8; ++nf) {
              acc[mf][nf] = __builtin_amdgcn_mfma_f32_16x16x32_bf16(
                  ah[mf], bf[nf], acc[mf][nf], 0, 0, 0);
              acc[mf][nf] = __builtin_amdgcn_mfma_f32_16x16x32_bf16(
                  al[mf], bf[nf], acc[mf][nf], 0, 0, 0);
            }
        }
      }

      const int fr = lane & 15, rg = lane >> 4;
#pragma unroll
      for (int mf = 0; mf < 4; ++mf)
#pragma unroll
        for (int nf = 0; nf < 8; ++nf) {
          int n = n0 + wn * 128 + nf * 16 + fr;
          float bb = bo[n];
#pragma unroll
          for (int j = 0; j < 4; ++j) {
            int m = m0 + wm * 64 + mf * 16 + rg * 4 + j;
            int orow = (m & 15) * 256 + (m >> 4);      // [b][s] row
            st_nt(&out[(size_t)orow * VOCAB + n], acc[mf][nf][j] + bb);
          }
        }
    }
  };

  // -------------------- master + helpers ----------------------------------
  if (blk >= MASTER) {
    if (blk == MASTER && tid == 0) {           // epoch publisher (replicated)
      int e0 = 0, e1 = 0;
      while (e0 < SEQ || e1 < SEQ) {
        int s0 = 0, s1 = 0;
#pragma unroll
        for (int i = 0; i < 4; ++i) s0 += ld_rlx(bar + i * 32);
#pragma unroll
        for (int i = 0; i < 8; ++i) s1 += ld_rlx(bar + (4 + i) * 32);
        int n0 = s0 >> 6;
        int n1 = s1 >> 7;
        if (n0 > e0) {
          e0 = n0;
#pragma unroll
          for (int i = 0; i < 8; ++i) st_rlx(bar + (12 + i) * 32, e0);
        }
        if (n1 > e1) {
          e1 = n1;
#pragma unroll
          for (int i = 0; i < 8; ++i) st_rlx(bar + (20 + i) * 32, e1);
        }
      }
    }
    proj_tiles();                              // helpers now; master after
    return;
  }

  // -------------------- scan blocks (r10 flow) -----------------------------
  float* wT   = (float*)pool;                  // 16384 floats
  float* hT   = wT + 16384;                    // 16384 floats
  float* part = hT + 16384;                    // 2048 floats
  float* bias = part + 2048;                   // 8 floats

  const bool isL0 = (blk < NL0);

  if (isL0) {
    const int j = blk;
#pragma unroll
    for (int p = 0; p < 8; ++p) {
      int idx = tid + 512 * p;
      int r = idx >> 8, kq = idx & 255;
      float4 v = *(const float4*)(Wh + ((size_t)(16 * j + r)) * HID + 4 * kq);
      wT[(4*kq+0)*16 + r] = v.x; wT[(4*kq+1)*16 + r] = v.y;
      wT[(4*kq+2)*16 + r] = v.z; wT[(4*kq+3)*16 + r] = v.w;
    }
  } else {
    const int j = blk - NL0;
#pragma unroll
    for (int p = 0; p < 8; ++p) {
      int idx = tid + 512 * p;
      int half = idx >> 11;
      int id2 = idx & 2047;
      int r = id2 >> 8, kq = id2 & 255;
      const float* W = (half ? Wh : Wi) + (size_t)HID * HID;
      float4 v = *(const float4*)(W + ((size_t)(8 * j + r)) * HID + 4 * kq);
      int kb = half * 1024 + 4 * kq;
      wT[(kb+0)*8 + r] = v.x; wT[(kb+1)*8 + r] = v.y;
      wT[(kb+2)*8 + r] = v.z; wT[(kb+3)*8 + r] = v.w;
    }
    if (tid < 8) bias[tid] = bi[HID + 8 * j + tid] + bh[HID + 8 * j + tid];
  }
  __syncthreads();

  const int sb  = tid & 15;
  const int skq = tid >> 4;
  auto hbase = [&](const float* src) {
    return (const float*)((const char*)src + sb * 4096 + skq * 16);
  };
  auto stage_write = [&](const f32x4* d) {
#pragma unroll
    for (int p = 0; p < 8; ++p) {
      int kq = skq + 32 * p;
#pragma unroll
      for (int c = 0; c < 4; ++c) hT[(4*kq+c)*16 + sb] = d[p][c];
    }
  };

  if (isL0) {
    // =============================== L0 ===================================
    const int bq = tid & 3, rq = (tid >> 2) & 3, ks = tid >> 4;  // ks 0..31
    for (int u = 0; u < SEQ; ++u) {
      float myPre = 0.f;               // gate-independent prefetch
      if (tid < 256)
        myPre = pre0[((size_t)u * BATCH + (tid >> 4)) * HID + 16 * blk + (tid & 15)];

      if (tid == 0) {
        while (ld_rlx(go0r) < u) __builtin_amdgcn_s_sleep(1);
        const int need = u - 7;
        if (need > 0)
          while (ld_rlx(go1r) < need) __builtin_amdgcn_s_sleep(1);
      }
      __syncthreads();

      f32x4 r0[8];
      LOAD8(r0, hbase(h0ring + ((u - 1) & 7) * BH));
      WAIT8(r0);
      stage_write(r0);
      __syncthreads();

      float acc[4][4] = {{0.f}};
#pragma unroll 4
      for (int i = 0; i < 32; ++i) {
        int k = ks + 32 * i;
        float4 hv = *(const float4*)&hT[k * 16 + 4 * bq];
        float4 wv = *(const float4*)&wT[k * 16 + 4 * rq];
        float hb[4] = {hv.x, hv.y, hv.z, hv.w};
        float wr[4] = {wv.x, wv.y, wv.z, wv.w};
#pragma unroll
        for (int b_ = 0; b_ < 4; ++b_)
#pragma unroll
          for (int rj = 0; rj < 4; ++rj)
            acc[b_][rj] = fmaf(hb[b_], wr[rj], acc[b_][rj]);
      }
#pragma unroll
      for (int b_ = 0; b_ < 4; ++b_)
#pragma unroll
        for (int rj = 0; rj < 4; ++rj) {
          float v = acc[b_][rj];
          v += __shfl_xor(v, 16); v += __shfl_xor(v, 32);
          acc[b_][rj] = v;
        }
      const int w = tid >> 6;
      if ((tid & 63) < 16) {
#pragma unroll
        for (int b_ = 0; b_ < 4; ++b_)
#pragma unroll
          for (int rj = 0; rj < 4; ++rj)
            part[w * 256 + (4*bq + b_) * 16 + 4*rq + rj] = acc[b_][rj];
      }
      __syncthreads();
      if (tid < 256) {
        int b = tid >> 4, r = tid & 15;
        float s = myPre;
#pragma unroll
        for (int w2 = 0; w2 < 8; ++w2) s += part[w2 * 256 + b * 16 + r];
        st_coherent(h0ring + (u & 7) * BH + (size_t)b * HID + 16 * blk + r, tanhf(s));
      }
      asm volatile("s_waitcnt vmcnt(0)" ::: "memory");
      __syncthreads();
      if (tid == 0)
        __hip_atomic_fetch_add(bar + (blk & 3) * 32, 1,
                               __ATOMIC_RELAXED, __HIP_MEMORY_SCOPE_AGENT);
    }
  } else {
    // =============================== L1 ===================================
    const int bq = tid & 3, rq = (tid >> 2) & 1, ks = tid >> 3;  // ks 0..63
    for (int t = 0; t < SEQ; ++t) {
      // ---- phase A (off critical chain): Wi1 . h0[t] ----
      if (tid == 0)
        while (ld_rlx(go0r) < t + 1) __builtin_amdgcn_s_sleep(1);
      __syncthreads();

      f32x4 r0[8];
      LOAD8(r0, hbase(h0ring + (t & 7) * BH));
      WAIT8(r0);
      stage_write(r0);
      __syncthreads();

      float acc[4][4] = {{0.f}};
#pragma unroll 4
      for (int i = 0; i < 16; ++i) {
        int k = ks + 64 * i;
        float4 hv = *(const float4*)&hT[k * 16 + 4 * bq];
        float4 wv = *(const float4*)&wT[k * 8 + 4 * rq];
        float hb[4] = {hv.x, hv.y, hv.z, hv.w};
        float wr[4] = {wv.x, wv.y, wv.z, wv.w};
#pragma unroll
        for (int b_ = 0; b_ < 4; ++b_)
#pragma unroll
          for (int rj = 0; rj < 4; ++rj)
            acc[b_][rj] = fmaf(hb[b_], wr[rj], acc[b_][rj]);
      }

      // ---- serial gate: h1[t-1] ready ----
      if (tid == 0 && t)
        while (ld_rlx(go1r) < t) __builtin_amdgcn_s_sleep(1);
      __syncthreads();                 // gate passed AND all done reading hT

      f32x4 r1[8];
      LOAD8(r1, hbase(h1g + ((t - 1) & 1) * BH));
      WAIT8(r1);
      stage_write(r1);
      __syncthreads();

      // ---- phase B: Wh1 . h1[t-1] ----
#pragma unroll 4
      for (int i = 0; i < 16; ++i) {
        int k = ks + 64 * i;
        float4 hv = *(const float4*)&hT[k * 16 + 4 * bq];
        float4 wv = *(const float4*)&wT[(1024 + k) * 8 + 4 * rq];
        float hb[4] = {hv.x, hv.y, hv.z, hv.w};
        float wr[4] = {wv.x, wv.y, wv.z, wv.w};
#pragma unroll
        for (int b_ = 0; b_ < 4; ++b_)
#pragma unroll
          for (int rj = 0; rj < 4; ++rj)
            acc[b_][rj] = fmaf(hb[b_], wr[rj], acc[b_][rj]);
      }
#pragma unroll
      for (int b_ = 0; b_ < 4; ++b_)
#pragma unroll
        for (int rj = 0; rj < 4; ++rj) {
          float v = acc[b_][rj];
          v += __shfl_xor(v, 8); v += __shfl_xor(v, 16); v += __shfl_xor(v, 32);
          acc[b_][rj] = v;
        }
      const int w = tid >> 6;
      if ((tid & 63) < 8) {
#pragma unroll
        for (int b_ = 0; b_ < 4; ++b_)
#pragma unroll
          for (int rj = 0; rj < 4; ++rj)
            part[w * 128 + (4*bq + b_) * 8 + 4*rq + rj] = acc[b_][rj];
      }
      __syncthreads();
      if (tid < 128) {
        int b = tid >> 3, r = tid & 7;
        float s = bias[r];
#pragma unroll
        for (int w2 = 0; w2 < 8; ++w2) s += part[w2 * 128 + b * 8 + r];
        int R = 8 * (blk - NL0) + r;
        float v = tanhf(s);
        // tops pre-split to bf16 hi/lo (same f2bf math proj used before)
        ushort hi = f2bf(v);
        ushort lo = f2bf(v - bf2f(hi));
        size_t mi = ((size_t)t * BATCH + b) * HID + R;
        st_coherent_u16(topsHi + mi, hi);
        st_coherent_u16(topsLo + mi, lo);
        st_coherent(h1g + (t & 1) * BH + (size_t)b * HID + R, v);
      }
      asm volatile("s_waitcnt vmcnt(0)" ::: "memory");
      __syncthreads();
      if (tid == 0)
        __hip_atomic_fetch_add(bar + (4 + (blk & 7)) * 32, 1,
                               __ATOMIC_RELAXED, __HIP_MEMORY_SCOPE_AGENT);
    }
  }

  // scan done for this block -> join the proj ticket queue
  __syncthreads();
  proj_tiles();
}

// hidden[0][b][n] = h0 step 255 (ring slot 7); hidden[1] = tops[255] (hi+lo)
__global__ void copy_hidden(const float* __restrict__ h0ring,
                            const ushort* __restrict__ topsHi,
                            const ushort* __restrict__ topsLo,
                            float* __restrict__ outh)
{
  int i = blockIdx.x * 256 + threadIdx.x;   // 0..32767
  int l = i >> 14, rem = i & 16383;         // rem = b*1024 + n
  if (l == 0) {
    outh[i] = h0ring[7 * BH + rem];
  } else {
    size_t mi = (size_t)(SEQ - 1) * BH + rem;
    outh[i] = bf2f(topsHi[mi]) + bf2f(topsLo[mi]);
  }
}

extern "C" void kernel_launch(void* const* d_in, const int* in_sizes, int n_in,
                              void* d_out, int out_size, void* d_ws, size_t ws_size,
                              hipStream_t stream)
{
  const int*   x     = (const int*)d_in[0];
  const float* embed = (const float*)d_in[1];
  const float* Wi    = (const float*)d_in[2];
  const float* bi    = (const float*)d_in[3];
  const float* Wh    = (const float*)d_in[4];
  const float* bh    = (const float*)d_in[5];
  const float* Wo    = (const float*)d_in[6];
  const float* bo    = (const float*)d_in[7];
  float* out = (float*)d_out;

  char* ws = (char*)d_ws;
  float*  pre0   = (float*) (ws);                          // 16 MiB
  ushort* topsHi = (ushort*)(ws + (16u << 20));            // 8 MiB
  ushort* topsLo = (ushort*)(ws + (24u << 20));            // 8 MiB
  float*  h0ring = (float*) (ws + (32u << 20));            // 512 KiB ring
  float*  h1g    = (float*) (ws + (32u << 20) + 524288);   // 128 KiB
  int*    bar    = (int*)   (ws + (32u << 20) + 655360);   // 4 KiB counters
  ushort* WoH    = (ushort*)(ws + (33u << 20));            // 64 MiB (optional)
  const size_t need_woh = (33ull << 20) + (size_t)VOCAB * HID * 2;
  const bool useWoH = ws_size >= need_woh;

  // zero ring + h1 parities + counters (deterministic across replays)
  hipMemsetAsync(h0ring, 0, 659456, stream);

  pre0_gemm<<<dim3(8, 32), dim3(256), 0, stream>>>(x, embed, Wi, bi, bh, pre0);
  if (useWoH)
    wo_conv<<<dim3(2048), dim3(256), 0, stream>>>(Wo, WoH);

  const ushort* WoHArg = useWoH ? WoH : (const ushort*)nullptr;
  void* args[] = { (void*)&Wi, (void*)&Wh, (void*)&bi, (void*)&bh,
                   (void*)&pre0, (void*)&h0ring, (void*)&h1g,
                   (void*)&topsHi, (void*)&topsLo, (void*)&Wo,
                   (void*)&WoHArg, (void*)&bo, (void*)&out, (void*)&bar };
  hipLaunchCooperativeKernel((void*)rnn_scan, dim3(NBLK), dim3(512), args, 0, stream);

  copy_hidden<<<dim3(128), dim3(256), 0, stream>>>(
      h0ring, topsHi, topsLo, out + (size_t)BATCH * SEQ * VOCAB);
}